// Round 14
// baseline (143.477 us; speedup 1.0000x reference)
//
#include <hip/hip_runtime.h>
#include <math.h>

static constexpr int BT  = 512;    // batch
static constexpr int TT  = 2048;   // time steps

// f64-derived constants, cast to f32 exactly as the reference does
static constexpr float C00 = (float)(1000.0 / (1.0 - 0.09));            // D[0][0]
static constexpr float C01 = (float)((1000.0 / (1.0 - 0.09)) * 0.3);    // D[0][1]
static constexpr float C22 = (float)((1000.0 / (1.0 - 0.09)) * 0.35);   // D[2][2]
static constexpr float INV3GH = (float)(1.0 / (3.0 * (1000.0 / 2.6) + 100.0));
static constexpr float SQ3 = 1.7320508075688772f;
static constexpr float IR3 = 0.57735026918962576f;

typedef float f2 __attribute__((ext_vector_type(2)));

__device__ __forceinline__ float softplus_f(float v) {
    return fmaxf(v, 0.0f) + log1pf(expf(-fabsf(v)));
}

// ---------------------------------------------------------------------------
// Fully fused (R11 structure): one b per 512-thread block; wave = p, lane = t.
// R13 kept: ping-pong red + overlapped reduce -> ONE barrier per window;
// packed-f32 projection (v_pk_fma_f32).
// R14 fix: red stride back to 51 (odd -> conflict-free scalar writes/reads;
// R13's stride 52 caused 4.7M bank conflicts), reduce reads scalar like R11.
// ---------------------------------------------------------------------------
__global__ __launch_bounds__(512) void k_fused(
    const float* __restrict__ x, const float* __restrict__ W11,
    const float* __restrict__ W12, const float* __restrict__ W2,
    float* __restrict__ out)
{
    __shared__ __align__(16) float w11s[16 * 36];   // [2p+h][36]
    __shared__ __align__(16) float w12d[24 * 36];   // [3p+j][36], D & sqrt3 folded
    __shared__ float w2s[144];                      // softplus(W2), xy col * IR3
    __shared__ __align__(16) float xs[2][64 * 36];  // double-buffered x window
    __shared__ float red[2][64 * 51];               // ping-pong [t][k*8+p], odd stride

    const int tid  = threadIdx.x;
    const int lane = tid & 63;     // t within window
    const int wv   = tid >> 6;     // p (0..7)
    const int b    = blockIdx.x;

    // ---- prologue: weights into LDS ----
    if (tid < 512) w11s[(tid >> 5) * 36 + (tid & 31)] = W11[tid];
    if (tid < 256) {
        int i = tid + 512;
        w11s[(i >> 5) * 36 + (i & 31)] = W11[i];
    }
    for (int i = tid; i < 768; i += 512) {
        int r = i >> 5, fc = i & 31;
        int p = r / 3, j = r - p * 3;
        const float* wb = W12 + p * 96 + fc;
        float v;
        if (j == 0)      v = C00 * wb[0]  + C01 * wb[32];
        else if (j == 1) v = C01 * wb[0]  + C00 * wb[32];
        else             v = (C22 * wb[64]) * SQ3;
        w12d[r * 36 + fc] = v;
    }
    if (tid < 144) {
        float v = softplus_f(W2[tid]);
        if ((tid % 24) % 3 == 2) v *= IR3;
        w2s[tid] = v;
    }
    // stage window 0
    const float4* xg4 = (const float4*)x + (size_t)b * (TT * 8);
    {
        float4 val = xg4[tid];
        int t = tid >> 3, c = tid & 7;
        *(float4*)&xs[0][t * 36 + 4 * c] = val;
    }
    __syncthreads();

    // wave-uniform W2 columns for this p
    float w2r0[6], w2r1[6], w2r2[6];
    #pragma unroll
    for (int k = 0; k < 6; ++k) {
        w2r0[k] = w2s[k * 24 + 3 * wv];
        w2r1[k] = w2s[k * 24 + 3 * wv + 1];
        w2r2[k] = w2s[k * 24 + 3 * wv + 2];
    }
    const float4* wa0 = (const float4*)(w11s + (2 * wv) * 36);
    const float4* wa1 = (const float4*)(w11s + (2 * wv + 1) * 36);
    const float4* wb0 = (const float4*)(w12d + (3 * wv) * 36);
    const float4* wb1 = (const float4*)(w12d + (3 * wv + 1) * 36);
    const float4* wb2 = (const float4*)(w12d + (3 * wv + 2) * 36);

    float Pxx = 0.f, Pyy = 0.f, Pxy = 0.f;
    float sigY = 10.f, sigY2 = 100.f, d0 = 0.f;

    for (int w = 0; w < 32; ++w) {
        // issue next window's x load early (latency hides under compute)
        float4 nval;
        const bool have = (w < 31);
        if (have) nval = xg4[(w + 1) * 512 + tid];

        // ---- projection, packed f32 pairs (v_pk_fma) ----
        const float* xr = &xs[w & 1][lane * 36];
        f2 dn2 = {0.f, 0.f}, ds2 = {0.f, 0.f};
        f2 e02 = {0.f, 0.f}, e12 = {0.f, 0.f}, e22 = {0.f, 0.f};
        #pragma unroll
        for (int c = 0; c < 8; ++c) {
            float4 xf = *(const float4*)(xr + 4 * c);
            float4 a0 = wa0[c], a1 = wa1[c];
            float4 b0 = wb0[c], b1 = wb1[c], b2 = wb2[c];
            f2 xlo = {xf.x, xf.y}, xhi = {xf.z, xf.w};
            f2 t0, t1;
            t0 = (f2){a0.x, a0.y}; t1 = (f2){a0.z, a0.w};
            dn2 = xlo * t0 + dn2;  dn2 = xhi * t1 + dn2;
            t0 = (f2){a1.x, a1.y}; t1 = (f2){a1.z, a1.w};
            ds2 = xlo * t0 + ds2;  ds2 = xhi * t1 + ds2;
            t0 = (f2){b0.x, b0.y}; t1 = (f2){b0.z, b0.w};
            e02 = xlo * t0 + e02;  e02 = xhi * t1 + e02;
            t0 = (f2){b1.x, b1.y}; t1 = (f2){b1.z, b1.w};
            e12 = xlo * t0 + e12;  e12 = xhi * t1 + e12;
            t0 = (f2){b2.x, b2.y}; t1 = (f2){b2.z, b2.w};
            e22 = xlo * t0 + e22;  e22 = xhi * t1 + e22;
        }
        float dn = dn2.x + dn2.y, ds = ds2.x + ds2.y;
        float e0 = e02.x + e02.y, e1 = e12.x + e12.y, e2 = e22.x + e22.y;

        float dnp  = fmaxf(dn, 0.f);
        float lam  = sqrtf(fmaf(dnp, dnp, fmaf(ds, ds, 1e-12f)));
        float dnew = (0.1f * (lam - 0.01f)) / (lam * 0.09f);
        dnew = fminf(fmaxf(dnew, 0.f), 1.f);

        // ---- window-parallel plastic scan (verified R10/R11 flow) ----
        float sxx = e0 - Pxx, syy = e1 - Pyy, sxy = e2 - Pxy;
        float q = fmaf(sxy, sxy, 1e-12f);   // sxy sqrt3-scaled
        q = fmaf(syy, syy, q);
        q = fmaf(sxx, sxx - syy, q);
        float f = 1.0f;

        unsigned long long mask = __ballot(q > sigY2);
        while (mask) {
            int ts = __ffsll((long long)mask) - 1;
            float qs  = __shfl(q, ts);
            float sxs = __shfl(sxx, ts);
            float sys = __shfl(syy, ts);
            float sps = __shfl(sxy, ts);
            float rq  = __builtin_amdgcn_rsqf(qs);
            float seq = qs * rq;
            float dk  = (seq - sigY) * INV3GH;
            float fn  = fmaf(100.f, dk, sigY);
            float fs  = fn * rq;
            float om  = 1.0f - fs;
            Pxx = fmaf(om, sxs, Pxx);
            Pyy = fmaf(om, sys, Pyy);
            Pxy = fmaf(om, sps, Pxy);
            sigY = fn; sigY2 = fn * fn;
            if (lane == ts) f = fs;
            bool redo = lane > ts;
            if (redo) {
                sxx = e0 - Pxx; syy = e1 - Pyy; sxy = e2 - Pxy;
                q = fmaf(sxy, sxy, 1e-12f);
                q = fmaf(syy, syy, q);
                q = fmaf(sxx, sxx - syy, q);
            }
            mask = __ballot(redo && (q > sigY2));
        }

        // damage: exclusive max-scan seeded by d0
        float m = dnew;
        #pragma unroll
        for (int off = 1; off < 64; off <<= 1) {
            float t2 = __shfl_up(m, off);
            if (lane >= off) m = fmaxf(m, t2);
        }
        float de = __shfl_up(m, 1);
        de = (lane == 0) ? d0 : fmaxf(d0, de);
        bool loading = dnew > de;
        float di = fmaxf(de, dnew);
        d0 = fmaxf(d0, __shfl(m, 63));

        float scale = loading ? f : f * (1.0f - di);
        float o0 = scale * sxx, o1 = scale * syy, o2 = scale * sxy;

        // ---- per-wave W2 partials -> red[w&1][t][k*8+p] (odd stride) ----
        #pragma unroll
        for (int k = 0; k < 6; ++k) {
            float cpk = fmaf(o0, w2r0[k], fmaf(o1, w2r1[k], o2 * w2r2[k]));
            red[w & 1][lane * 51 + k * 8 + wv] = cpk;
        }

        // ---- overlapped reduce of the PREVIOUS window (scalar reads) ----
        if (w > 0 && tid < 384) {
            int t = tid & 63, k = tid >> 6;
            const float* rp = &red[(w - 1) & 1][t * 51 + k * 8];
            float acc = ((rp[0] + rp[1]) + (rp[2] + rp[3]))
                      + ((rp[4] + rp[5]) + (rp[6] + rp[7]));
            out[((size_t)b * TT + (w - 1) * 64 + t) * 6 + k] = acc;
        }

        // write next window's stage (disjoint buffer)
        if (have) {
            int t = tid >> 3, c = tid & 7;
            *(float4*)&xs[(w + 1) & 1][t * 36 + 4 * c] = nval;
        }
        __syncthreads();   // the ONLY barrier per window
    }

    // epilogue: reduce window 31
    if (tid < 384) {
        int t = tid & 63, k = tid >> 6;
        const float* rp = &red[1][t * 51 + k * 8];
        float acc = ((rp[0] + rp[1]) + (rp[2] + rp[3]))
                  + ((rp[4] + rp[5]) + (rp[6] + rp[7]));
        out[((size_t)b * TT + 31 * 64 + t) * 6 + k] = acc;
    }
}

extern "C" void kernel_launch(void* const* d_in, const int* in_sizes, int n_in,
                              void* d_out, int out_size, void* d_ws, size_t ws_size,
                              hipStream_t stream)
{
    const float* x   = (const float*)d_in[0];
    const float* W11 = (const float*)d_in[1];
    const float* W12 = (const float*)d_in[2];
    const float* W2  = (const float*)d_in[3];
    float* out = (float*)d_out;

    hipLaunchKernelGGL(k_fused, dim3(BT), dim3(512), 0, stream,
                       x, W11, W12, W2, out);
}

// Round 15
// 119.768 us; speedup vs baseline: 1.1980x; 1.1980x over previous
//
#include <hip/hip_runtime.h>
#include <math.h>

static constexpr int BT  = 512;    // batch
static constexpr int TT  = 2048;   // time steps

// f64-derived constants, cast to f32 exactly as the reference does
static constexpr float C00 = (float)(1000.0 / (1.0 - 0.09));            // D[0][0]
static constexpr float C01 = (float)((1000.0 / (1.0 - 0.09)) * 0.3);    // D[0][1]
static constexpr float C22 = (float)((1000.0 / (1.0 - 0.09)) * 0.35);   // D[2][2]
static constexpr float INV3GH = (float)(1.0 / (3.0 * (1000.0 / 2.6) + 100.0));
static constexpr float SQ3 = 1.7320508075688772f;
static constexpr float IR3 = 0.57735026918962576f;

typedef float f2 __attribute__((ext_vector_type(2)));

__device__ __forceinline__ float softplus_f(float v) {
    return fmaxf(v, 0.0f) + log1pf(expf(-fabsf(v)));
}

// Ballot-driven plastic window (verified R10..R14 flow), exact serial order.
__device__ __forceinline__ void plastic_window(
    float e0, float e1, float e2, int lane,
    float& Pxx, float& Pyy, float& Pxy, float& sigY, float& sigY2,
    float& sxx, float& syy, float& sxy, float& f)
{
    sxx = e0 - Pxx; syy = e1 - Pyy; sxy = e2 - Pxy;
    float q = fmaf(sxy, sxy, 1e-12f);   // sxy sqrt3-scaled
    q = fmaf(syy, syy, q);
    q = fmaf(sxx, sxx - syy, q);
    f = 1.0f;
    unsigned long long mask = __ballot(q > sigY2);
    while (mask) {
        int ts = __ffsll((long long)mask) - 1;
        float qs  = __shfl(q, ts);
        float sxs = __shfl(sxx, ts);
        float sys = __shfl(syy, ts);
        float sps = __shfl(sxy, ts);
        float rq  = __builtin_amdgcn_rsqf(qs);
        float seq = qs * rq;
        float dk  = (seq - sigY) * INV3GH;
        float fn  = fmaf(100.f, dk, sigY);
        float fs  = fn * rq;
        float om  = 1.0f - fs;
        Pxx = fmaf(om, sxs, Pxx);
        Pyy = fmaf(om, sys, Pyy);
        Pxy = fmaf(om, sps, Pxy);
        sigY = fn; sigY2 = fn * fn;
        if (lane == ts) f = fs;
        bool redo = lane > ts;
        if (redo) {
            sxx = e0 - Pxx; syy = e1 - Pyy; sxy = e2 - Pxy;
            q = fmaf(sxy, sxy, 1e-12f);
            q = fmaf(syy, syy, q);
            q = fmaf(sxx, sxx - syy, q);
        }
        mask = __ballot(redo && (q > sigY2));
    }
}

// ---------------------------------------------------------------------------
// Fully fused, 2-WINDOW SUPERSTEP: one b per 512-thread block; wave=p, lane=t.
// Per superstep (windows w0=2s, w1=2s+1):
//  - projection of BOTH windows sharing each weight b128 read (40 -> 20/win)
//  - damage max-scans of both windows interleaved (2x shfl ILP)
//  - ballot plastic loops in exact serial order (w0 fully before w1)
//  - red[0],red[1] written; one barrier; reduce both + stage next 2 windows
// LDS ~69 KB -> 2 blocks/CU. Math order identical to R14 (absmax ~0.25).
// ---------------------------------------------------------------------------
__global__ __launch_bounds__(512) void k_fused(
    const float* __restrict__ x, const float* __restrict__ W11,
    const float* __restrict__ W12, const float* __restrict__ W2,
    float* __restrict__ out)
{
    __shared__ __align__(16) float w11s[16 * 36];   // [2p+h][36]
    __shared__ __align__(16) float w12d[24 * 36];   // [3p+j][36], D & sqrt3 folded
    __shared__ float w2s[144];                      // softplus(W2), xy col * IR3
    __shared__ __align__(16) float xs[4][64 * 36];  // 4-deep x window ring
    __shared__ float red[2][64 * 51];               // [win-in-superstep][t][k*8+p]

    const int tid  = threadIdx.x;
    const int lane = tid & 63;     // t within window
    const int wv   = tid >> 6;     // p (0..7)
    const int b    = blockIdx.x;

    // ---- prologue: weights into LDS ----
    if (tid < 512) w11s[(tid >> 5) * 36 + (tid & 31)] = W11[tid];
    if (tid < 256) {
        int i = tid + 512;
        w11s[(i >> 5) * 36 + (i & 31)] = W11[i];
    }
    for (int i = tid; i < 768; i += 512) {
        int r = i >> 5, fc = i & 31;
        int p = r / 3, j = r - p * 3;
        const float* wb = W12 + p * 96 + fc;
        float v;
        if (j == 0)      v = C00 * wb[0]  + C01 * wb[32];
        else if (j == 1) v = C01 * wb[0]  + C00 * wb[32];
        else             v = (C22 * wb[64]) * SQ3;
        w12d[r * 36 + fc] = v;
    }
    if (tid < 144) {
        float v = softplus_f(W2[tid]);
        if ((tid % 24) % 3 == 2) v *= IR3;
        w2s[tid] = v;
    }
    // stage windows 0 and 1
    const float4* xg4 = (const float4*)x + (size_t)b * (TT * 8);
    {
        int t = tid >> 3, c = tid & 7;
        float4 v0 = xg4[tid];
        float4 v1 = xg4[512 + tid];
        *(float4*)&xs[0][t * 36 + 4 * c] = v0;
        *(float4*)&xs[1][t * 36 + 4 * c] = v1;
    }
    __syncthreads();

    // wave-uniform W2 columns for this p
    float w2r0[6], w2r1[6], w2r2[6];
    #pragma unroll
    for (int k = 0; k < 6; ++k) {
        w2r0[k] = w2s[k * 24 + 3 * wv];
        w2r1[k] = w2s[k * 24 + 3 * wv + 1];
        w2r2[k] = w2s[k * 24 + 3 * wv + 2];
    }
    const float4* wa0 = (const float4*)(w11s + (2 * wv) * 36);
    const float4* wa1 = (const float4*)(w11s + (2 * wv + 1) * 36);
    const float4* wb0 = (const float4*)(w12d + (3 * wv) * 36);
    const float4* wb1 = (const float4*)(w12d + (3 * wv + 1) * 36);
    const float4* wb2 = (const float4*)(w12d + (3 * wv + 2) * 36);

    float Pxx = 0.f, Pyy = 0.f, Pxy = 0.f;
    float sigY = 10.f, sigY2 = 100.f, d0 = 0.f;

    for (int s = 0; s < 16; ++s) {
        const int w0 = 2 * s, w1 = w0 + 1;
        const bool have = (s < 15);
        float4 nv0, nv1;
        if (have) {
            nv0 = xg4[(w0 + 2) * 512 + tid];
            nv1 = xg4[(w1 + 2) * 512 + tid];
        }

        // ---- projection of BOTH windows, shared weight reads ----
        const float* xr0 = &xs[w0 & 3][lane * 36];
        const float* xr1 = &xs[w1 & 3][lane * 36];
        f2 dnA = {0,0}, dsA = {0,0}, e0A = {0,0}, e1A = {0,0}, e2A = {0,0};
        f2 dnB = {0,0}, dsB = {0,0}, e0B = {0,0}, e1B = {0,0}, e2B = {0,0};
        #pragma unroll
        for (int c = 0; c < 8; ++c) {
            float4 a0 = wa0[c], a1 = wa1[c];
            float4 b0 = wb0[c], b1 = wb1[c], b2 = wb2[c];
            float4 xf0 = *(const float4*)(xr0 + 4 * c);
            float4 xf1 = *(const float4*)(xr1 + 4 * c);
            f2 xlo0 = {xf0.x, xf0.y}, xhi0 = {xf0.z, xf0.w};
            f2 xlo1 = {xf1.x, xf1.y}, xhi1 = {xf1.z, xf1.w};
            f2 t0, t1;
            t0 = (f2){a0.x, a0.y}; t1 = (f2){a0.z, a0.w};
            dnA = xlo0 * t0 + dnA;  dnA = xhi0 * t1 + dnA;
            dnB = xlo1 * t0 + dnB;  dnB = xhi1 * t1 + dnB;
            t0 = (f2){a1.x, a1.y}; t1 = (f2){a1.z, a1.w};
            dsA = xlo0 * t0 + dsA;  dsA = xhi0 * t1 + dsA;
            dsB = xlo1 * t0 + dsB;  dsB = xhi1 * t1 + dsB;
            t0 = (f2){b0.x, b0.y}; t1 = (f2){b0.z, b0.w};
            e0A = xlo0 * t0 + e0A;  e0A = xhi0 * t1 + e0A;
            e0B = xlo1 * t0 + e0B;  e0B = xhi1 * t1 + e0B;
            t0 = (f2){b1.x, b1.y}; t1 = (f2){b1.z, b1.w};
            e1A = xlo0 * t0 + e1A;  e1A = xhi0 * t1 + e1A;
            e1B = xlo1 * t0 + e1B;  e1B = xhi1 * t1 + e1B;
            t0 = (f2){b2.x, b2.y}; t1 = (f2){b2.z, b2.w};
            e2A = xlo0 * t0 + e2A;  e2A = xhi0 * t1 + e2A;
            e2B = xlo1 * t0 + e2B;  e2B = xhi1 * t1 + e2B;
        }
        float dn0 = dnA.x + dnA.y, ds0 = dsA.x + dsA.y;
        float e00 = e0A.x + e0A.y, e10 = e1A.x + e1A.y, e20 = e2A.x + e2A.y;
        float dn1 = dnB.x + dnB.y, ds1 = dsB.x + dsB.y;
        float e01 = e0B.x + e0B.y, e11 = e1B.x + e1B.y, e21 = e2B.x + e2B.y;

        float dnp0  = fmaxf(dn0, 0.f);
        float lam0  = sqrtf(fmaf(dnp0, dnp0, fmaf(ds0, ds0, 1e-12f)));
        float dnew0 = (0.1f * (lam0 - 0.01f)) / (lam0 * 0.09f);
        dnew0 = fminf(fmaxf(dnew0, 0.f), 1.f);
        float dnp1  = fmaxf(dn1, 0.f);
        float lam1  = sqrtf(fmaf(dnp1, dnp1, fmaf(ds1, ds1, 1e-12f)));
        float dnew1 = (0.1f * (lam1 - 0.01f)) / (lam1 * 0.09f);
        dnew1 = fminf(fmaxf(dnew1, 0.f), 1.f);

        // ---- damage max-scans, two windows interleaved (2x ILP) ----
        float m0 = dnew0, m1 = dnew1;
        #pragma unroll
        for (int off = 1; off < 64; off <<= 1) {
            float t0 = __shfl_up(m0, off);
            float t1 = __shfl_up(m1, off);
            if (lane >= off) { m0 = fmaxf(m0, t0); m1 = fmaxf(m1, t1); }
        }
        float de0 = __shfl_up(m0, 1);
        de0 = (lane == 0) ? d0 : fmaxf(d0, de0);
        bool loading0 = dnew0 > de0;
        float di0 = fmaxf(de0, dnew0);
        float d0a = fmaxf(d0, __shfl(m0, 63));     // d after window w0
        float de1 = __shfl_up(m1, 1);
        de1 = (lane == 0) ? d0a : fmaxf(d0a, de1);
        bool loading1 = dnew1 > de1;
        float di1 = fmaxf(de1, dnew1);
        d0 = fmaxf(d0a, __shfl(m1, 63));

        // ---- plastic loops, exact serial order: w0 fully before w1 ----
        float sxx0, syy0, sxy0, f0;
        plastic_window(e00, e10, e20, lane, Pxx, Pyy, Pxy, sigY, sigY2,
                       sxx0, syy0, sxy0, f0);
        float scale0 = loading0 ? f0 : f0 * (1.0f - di0);
        float o00 = scale0 * sxx0, o10 = scale0 * syy0, o20 = scale0 * sxy0;

        float sxx1, syy1, sxy1, f1;
        plastic_window(e01, e11, e21, lane, Pxx, Pyy, Pxy, sigY, sigY2,
                       sxx1, syy1, sxy1, f1);
        float scale1 = loading1 ? f1 : f1 * (1.0f - di1);
        float o01 = scale1 * sxx1, o11 = scale1 * syy1, o21 = scale1 * sxy1;

        // ---- per-wave W2 partials for both windows ----
        #pragma unroll
        for (int k = 0; k < 6; ++k) {
            float c0 = fmaf(o00, w2r0[k], fmaf(o10, w2r1[k], o20 * w2r2[k]));
            float c1 = fmaf(o01, w2r0[k], fmaf(o11, w2r1[k], o21 * w2r2[k]));
            red[0][lane * 51 + k * 8 + wv] = c0;
            red[1][lane * 51 + k * 8 + wv] = c1;
        }
        __syncthreads();

        // ---- reduce both windows + stage next superstep's x ----
        if (tid < 384) {
            int t = tid & 63, k = tid >> 6;
            const float* rp0 = &red[0][t * 51 + k * 8];
            float a0 = ((rp0[0] + rp0[1]) + (rp0[2] + rp0[3]))
                     + ((rp0[4] + rp0[5]) + (rp0[6] + rp0[7]));
            out[((size_t)b * TT + w0 * 64 + t) * 6 + k] = a0;
            const float* rp1 = &red[1][t * 51 + k * 8];
            float a1 = ((rp1[0] + rp1[1]) + (rp1[2] + rp1[3]))
                     + ((rp1[4] + rp1[5]) + (rp1[6] + rp1[7]));
            out[((size_t)b * TT + w1 * 64 + t) * 6 + k] = a1;
        }
        if (have) {
            int t = tid >> 3, c = tid & 7;
            *(float4*)&xs[(w0 + 2) & 3][t * 36 + 4 * c] = nv0;
            *(float4*)&xs[(w1 + 2) & 3][t * 36 + 4 * c] = nv1;
        }
        __syncthreads();
    }
}

extern "C" void kernel_launch(void* const* d_in, const int* in_sizes, int n_in,
                              void* d_out, int out_size, void* d_ws, size_t ws_size,
                              hipStream_t stream)
{
    const float* x   = (const float*)d_in[0];
    const float* W11 = (const float*)d_in[1];
    const float* W12 = (const float*)d_in[2];
    const float* W2  = (const float*)d_in[3];
    float* out = (float*)d_out;

    hipLaunchKernelGGL(k_fused, dim3(BT), dim3(512), 0, stream,
                       x, W11, W12, W2, out);
}